// Round 2
// baseline (84.321 us; speedup 1.0000x reference)
//
#include <hip/hip_runtime.h>

#define C_IN  32
#define O_OUT 48
#define H_IN  96
#define W_IN  96
#define H_OUT 192
#define W_OUT 192
#define HW_IN (H_IN * W_IN)

// ---------------------------------------------------------------------------
// Main kernel: computes ALL output pixels assuming interior norm classes and
// clamped x reads. Only the 1-pixel output frame (ho or wo in {0,191}) is
// wrong; nct_fix overwrites it afterwards.
//
// Even out row 2s  uses taps i in {1,3} -> x rows {s, s-1}
// Odd  out row 2s+1 uses taps i in {0,2} -> x rows {s+1, s}
// Interior reciprocal norms per parity pair get folded into the weights:
//   w_hat[i][j] = w[i][j] / sum_{i' same row-parity-class, j' same col-class} w[i'][j']
// ---------------------------------------------------------------------------
__global__ __launch_bounds__(192) void nct_main(
    const float* __restrict__ x,      // [B,32,96,96]
    const float* __restrict__ weight, // [48,32,4,4]
    const float* __restrict__ bias,   // [48]
    float* __restrict__ out)          // [B,48,192,192]
{
    __shared__ float wl[C_IN][16];
    __shared__ float ws[C_IN][16];  // prescaled weights

    const int zid = blockIdx.z;         // b*48 + o
    const int b   = zid / O_OUT;
    const int o   = zid % O_OUT;

    const int tx  = threadIdx.x;        // 0..23
    const int ty  = threadIdx.y;        // 0..7
    const int tid = ty * 24 + tx;

    // stage raw weights
    {
        const float* wsrc = weight + (size_t)o * (C_IN * 16);
        for (int i = tid; i < C_IN * 16; i += 192)
            ((float*)wl)[i] = wsrc[i];
    }
    __syncthreads();

    // prescale by interior reciprocal norms
    for (int idx = tid; idx < C_IN * 16; idx += 192) {
        const int c = idx >> 4, tap = idx & 15;
        const int i = tap >> 2, j = tap & 3;
        const float* wc = wl[c];
        float nsum;
        if (i & 1) {            // even-out-row taps (i in {1,3})
            if (j & 1) nsum = wc[5] + wc[7] + wc[13] + wc[15];   // cols {1,3}
            else       nsum = wc[4] + wc[6] + wc[12] + wc[14];   // cols {0,2}
        } else {                // odd-out-row taps (i in {0,2})
            if (j & 1) nsum = wc[1] + wc[3] + wc[9]  + wc[11];
            else       nsum = wc[0] + wc[2] + wc[8]  + wc[10];
        }
        ws[c][tap] = wc[tap] / nsum;
    }
    __syncthreads();

    const int row = blockIdx.x * 8 + ty;   // input row in [0,96)
    const int t0  = tx * 4;                // input col base (float4-aligned)

    const int rm = (row > 0)          ? row - 1 : 0;
    const int rp = (row < H_IN - 1)   ? row + 1 : H_IN - 1;
    const int cm = (t0 > 0)           ? t0 - 1  : 0;
    const int cp = (t0 + 4 < W_IN)    ? t0 + 4  : W_IN - 1;

    const float* xb = x + (size_t)b * (C_IN * HW_IN);
    const float* pm = xb + rm  * W_IN;
    const float* p0 = xb + row * W_IN;
    const float* pp = xb + rp  * W_IN;

    float ae[4] = {0, 0, 0, 0}, be[4] = {0, 0, 0, 0};
    float ao[4] = {0, 0, 0, 0}, bq[4] = {0, 0, 0, 0};

    for (int c = 0; c < C_IN; ++c) {
        const float4 xm4 = *(const float4*)(pm + t0);
        const float  xmm = pm[cm], xmp = pm[cp];
        const float4 x04 = *(const float4*)(p0 + t0);
        const float  x0m = p0[cm], x0p = p0[cp];
        const float4 xp4 = *(const float4*)(pp + t0);
        const float  xpm = pp[cm], xpp = pp[cp];

        const float4* wc4 = (const float4*)ws[c];
        const float4 w0 = wc4[0], w1 = wc4[1], w2 = wc4[2], w3 = wc4[3];

        const float xm_[6] = {xmm, xm4.x, xm4.y, xm4.z, xm4.w, xmp};
        const float x0_[6] = {x0m, x04.x, x04.y, x04.z, x04.w, x0p};
        const float xp_[6] = {xpm, xp4.x, xp4.y, xp4.z, xp4.w, xpp};

        #pragma unroll
        for (int k = 0; k < 4; ++k) {
            // out(2s, 2(t0+k))   : x[s][t]*w11 + x[s][t-1]*w13 + x[s-1][t]*w31 + x[s-1][t-1]*w33
            ae[k] += x0_[k + 1] * w1.y + x0_[k] * w1.w + xm_[k + 1] * w3.y + xm_[k] * w3.w;
            // out(2s, 2(t0+k)+1) : x[s][t+1]*w10 + x[s][t]*w12 + x[s-1][t+1]*w30 + x[s-1][t]*w32
            be[k] += x0_[k + 2] * w1.x + x0_[k + 1] * w1.z + xm_[k + 2] * w3.x + xm_[k + 1] * w3.z;
            // out(2s+1, 2(t0+k)) : x[s+1]*w01/w03 + x[s]*w21/w23
            ao[k] += xp_[k + 1] * w0.y + xp_[k] * w0.w + x0_[k + 1] * w2.y + x0_[k] * w2.w;
            // out(2s+1, 2(t0+k)+1)
            bq[k] += xp_[k + 2] * w0.x + xp_[k + 1] * w0.z + x0_[k + 2] * w2.x + x0_[k + 1] * w2.z;
        }

        pm += HW_IN; p0 += HW_IN; pp += HW_IN;
    }

    const float bv = bias[o];
    float* orow = out + ((size_t)zid * H_OUT + 2 * row) * W_OUT + 2 * t0;

    float4 e0 = make_float4(ae[0] + bv, be[0] + bv, ae[1] + bv, be[1] + bv);
    float4 e1 = make_float4(ae[2] + bv, be[2] + bv, ae[3] + bv, be[3] + bv);
    float4 q0 = make_float4(ao[0] + bv, bq[0] + bv, ao[1] + bv, bq[1] + bv);
    float4 q1 = make_float4(ao[2] + bv, bq[2] + bv, ao[3] + bv, bq[3] + bv);

    *(float4*)(orow)             = e0;
    *(float4*)(orow + 4)         = e1;
    *(float4*)(orow + W_OUT)     = q0;
    *(float4*)(orow + W_OUT + 4) = q1;
}

// ---------------------------------------------------------------------------
// Frame fixup: exact recomputation of the 764 frame pixels per (b,o),
// with true zero-padding semantics and per-class norms.
// ---------------------------------------------------------------------------
__global__ __launch_bounds__(256) void nct_fix(
    const float* __restrict__ x,
    const float* __restrict__ weight,
    const float* __restrict__ bias,
    float* __restrict__ out)
{
    const int z = blockIdx.y;
    const int b = z / O_OUT;
    const int o = z % O_OUT;

    const int p = blockIdx.x * 256 + threadIdx.x;
    if (p >= 764) return;

    int ho, wo;
    if      (p < 192) { ho = 0;             wo = p;       }
    else if (p < 384) { ho = 191;           wo = p - 192; }
    else if (p < 574) { ho = 1 + (p - 384); wo = 0;       }
    else              { ho = 1 + (p - 574); wo = 191;     }

    const int s = ho >> 1, t = wo >> 1;

    int ii[2], ri[2], nr = 0;
    if (ho & 1) { ii[nr] = 2; ri[nr] = s; ++nr; if (s + 1 < H_IN) { ii[nr] = 0; ri[nr] = s + 1; ++nr; } }
    else        { ii[nr] = 1; ri[nr] = s; ++nr; if (s     >= 1  ) { ii[nr] = 3; ri[nr] = s - 1; ++nr; } }
    int jj[2], cj[2], nc = 0;
    if (wo & 1) { jj[nc] = 2; cj[nc] = t; ++nc; if (t + 1 < W_IN) { jj[nc] = 0; cj[nc] = t + 1; ++nc; } }
    else        { jj[nc] = 1; cj[nc] = t; ++nc; if (t     >= 1  ) { jj[nc] = 3; cj[nc] = t - 1; ++nc; } }

    const float* xb = x + (size_t)b * (C_IN * HW_IN);
    const float* wb = weight + (size_t)o * (C_IN * 16);

    float acc = 0.f;
    for (int c = 0; c < C_IN; ++c) {
        const float* xc = xb + c * HW_IN;
        const float* wc = wb + c * 16;
        float y = 0.f, n = 0.f;
        for (int a = 0; a < nr; ++a)
            for (int d = 0; d < nc; ++d) {
                const float wv = wc[ii[a] * 4 + jj[d]];
                y += wv * xc[ri[a] * W_IN + cj[d]];
                n += wv;
            }
        acc += y / n;
    }
    out[((size_t)z * H_OUT + ho) * W_OUT + wo] = acc + bias[o];
}

extern "C" void kernel_launch(void* const* d_in, const int* in_sizes, int n_in,
                              void* d_out, int out_size, void* d_ws, size_t ws_size,
                              hipStream_t stream) {
    const float* x    = (const float*)d_in[0];
    const float* w    = (const float*)d_in[1];
    const float* bias = (const float*)d_in[2];
    float* out = (float*)d_out;

    dim3 bmain(24, 8, 1);
    dim3 gmain(H_IN / 8, 1, 2 * O_OUT);   // 12 x 1 x 96
    hipLaunchKernelGGL(nct_main, gmain, bmain, 0, stream, x, w, bias, out);

    dim3 bfix(256, 1, 1);
    dim3 gfix(3, 2 * O_OUT, 1);           // 3 x 96
    hipLaunchKernelGGL(nct_fix, gfix, bfix, 0, stream, x, w, bias, out);
}

// Round 3
// 46.837 us; speedup vs baseline: 1.8003x; 1.8003x over previous
//
#include <hip/hip_runtime.h>

#define C_IN  32
#define O_OUT 48
#define H_IN  96
#define W_IN  96
#define H_OUT 192
#define W_OUT 192
#define HW_IN (H_IN * W_IN)
#define O_TILE 4

// ---------------------------------------------------------------------------
// Main kernel: all output pixels with interior norm folded into weights and
// clamped x reads. Wrong only on the 1-pixel output frame; nct_fix repairs it.
// Even out row 2s   uses taps i in {1,3} -> x rows {s, s-1}
// Odd  out row 2s+1 uses taps i in {0,2} -> x rows {s+1, s}
// ---------------------------------------------------------------------------
__global__ __launch_bounds__(256) void nct_main(
    const float* __restrict__ x,      // [B,32,96,96]
    const float* __restrict__ weight, // [48,32,4,4]
    const float* __restrict__ bias,   // [48]
    float* __restrict__ out)          // [B,48,192,192]
{
    __shared__ float wl[O_TILE][C_IN][16];
    __shared__ float ws[O_TILE][C_IN][16];

    const int b  = blockIdx.z;
    const int o0 = blockIdx.y * O_TILE;

    const int tx  = threadIdx.x;   // 0..15
    const int ty  = threadIdx.y;   // 0..15
    const int tid = ty * 16 + tx;

    // stage raw weights for O_TILE o's (2048 floats)
    {
        const float* wsrc = weight + (size_t)o0 * (C_IN * 16);
        #pragma unroll
        for (int i = 0; i < O_TILE * C_IN * 16 / 256; ++i)
            ((float*)wl)[tid + i * 256] = wsrc[tid + i * 256];
    }
    __syncthreads();

    // prescale by interior reciprocal norms
    #pragma unroll
    for (int k = 0; k < O_TILE * C_IN * 16 / 256; ++k) {
        const int idx = tid + k * 256;
        const int oc  = idx >> 4;          // combined (oi*C_IN + c)
        const int tap = idx & 15;
        const int i = tap >> 2, j = tap & 3;
        const float* wc = ((const float*)wl) + oc * 16;
        float nsum;
        if (i & 1) {   // even-out-row taps (rows 1,3)
            nsum = (j & 1) ? (wc[5] + wc[7] + wc[13] + wc[15])
                           : (wc[4] + wc[6] + wc[12] + wc[14]);
        } else {       // odd-out-row taps (rows 0,2)
            nsum = (j & 1) ? (wc[1] + wc[3] + wc[9] + wc[11])
                           : (wc[0] + wc[2] + wc[8] + wc[10]);
        }
        ((float*)ws)[idx] = wc[tap] / nsum;
    }
    __syncthreads();

    const int s = (blockIdx.x / 6) * 16 + ty;   // input row
    const int t = (blockIdx.x % 6) * 16 + tx;   // input col

    const int rm = (s > 0)        ? s - 1 : 0;
    const int rp = (s < H_IN - 1) ? s + 1 : H_IN - 1;
    const int cm = (t > 0)        ? t - 1 : 0;
    const int cp = (t < W_IN - 1) ? t + 1 : W_IN - 1;

    const float* xb = x + (size_t)b * (C_IN * HW_IN);
    const float* pm = xb + rm * W_IN;
    const float* p0 = xb + s  * W_IN;
    const float* pp = xb + rp * W_IN;

    float acc[O_TILE][4];
    #pragma unroll
    for (int oi = 0; oi < O_TILE; ++oi)
        #pragma unroll
        for (int k = 0; k < 4; ++k) acc[oi][k] = 0.f;

    #pragma unroll 2
    for (int c = 0; c < C_IN; ++c) {
        const float xmm = pm[cm], xm0 = pm[t], xmp = pm[cp];
        const float x0m = p0[cm], x00 = p0[t], x0p = p0[cp];
        const float xpm = pp[cm], xp0 = pp[t], xpp = pp[cp];

        #pragma unroll
        for (int oi = 0; oi < O_TILE; ++oi) {
            const float4* wc4 = (const float4*)ws[oi][c];
            const float4 w0 = wc4[0], w1 = wc4[1], w2 = wc4[2], w3 = wc4[3];
            acc[oi][0] += x00 * w1.y + x0m * w1.w + xm0 * w3.y + xmm * w3.w;
            acc[oi][1] += x0p * w1.x + x00 * w1.z + xmp * w3.x + xm0 * w3.z;
            acc[oi][2] += xp0 * w0.y + xpm * w0.w + x00 * w2.y + x0m * w2.w;
            acc[oi][3] += xpp * w0.x + xp0 * w0.z + x0p * w2.x + x00 * w2.z;
        }
        pm += HW_IN; p0 += HW_IN; pp += HW_IN;
    }

    #pragma unroll
    for (int oi = 0; oi < O_TILE; ++oi) {
        const float bv = bias[o0 + oi];
        float* op = out + ((size_t)((b * O_OUT + o0 + oi) * H_OUT) + 2 * s) * W_OUT + 2 * t;
        *(float2*)(op)         = make_float2(acc[oi][0] + bv, acc[oi][1] + bv);
        *(float2*)(op + W_OUT) = make_float2(acc[oi][2] + bv, acc[oi][3] + bv);
    }
}

// ---------------------------------------------------------------------------
// Frame fixup: exact recompute of the 764 frame pixels per (b,o) with true
// zero-padding and per-class norms. 8 lanes share one pixel (4 channels each),
// shfl_xor reduce.
// ---------------------------------------------------------------------------
__global__ __launch_bounds__(256) void nct_fix(
    const float* __restrict__ x,
    const float* __restrict__ weight,
    const float* __restrict__ bias,
    float* __restrict__ out)
{
    const int z = blockIdx.y;
    const int b = z / O_OUT;
    const int o = z % O_OUT;

    const int tid = threadIdx.x;
    const int pl  = tid >> 3;          // 0..31: pixel slot
    const int cg  = tid & 7;           // channel group
    const int p   = blockIdx.x * 32 + pl;

    float acc = 0.f;
    int ho = 0, wo = 0;
    const bool valid = (p < 764);
    if (valid) {
        if      (p < 192) { ho = 0;             wo = p;       }
        else if (p < 384) { ho = 191;           wo = p - 192; }
        else if (p < 574) { ho = 1 + (p - 384); wo = 0;       }
        else              { ho = 1 + (p - 574); wo = 191;     }

        const int s = ho >> 1, t = wo >> 1;

        int ii[2], ri[2], nr = 0;
        if (ho & 1) { ii[nr] = 2; ri[nr] = s; ++nr; if (s + 1 < H_IN) { ii[nr] = 0; ri[nr] = s + 1; ++nr; } }
        else        { ii[nr] = 1; ri[nr] = s; ++nr; if (s     >= 1  ) { ii[nr] = 3; ri[nr] = s - 1; ++nr; } }
        int jj[2], cj[2], nc = 0;
        if (wo & 1) { jj[nc] = 2; cj[nc] = t; ++nc; if (t + 1 < W_IN) { jj[nc] = 0; cj[nc] = t + 1; ++nc; } }
        else        { jj[nc] = 1; cj[nc] = t; ++nc; if (t     >= 1  ) { jj[nc] = 3; cj[nc] = t - 1; ++nc; } }

        const float* xb = x + (size_t)b * (C_IN * HW_IN);
        const float* wb = weight + (size_t)o * (C_IN * 16);

        #pragma unroll
        for (int cc = 0; cc < 4; ++cc) {
            const int c = cg * 4 + cc;
            const float* xc = xb + c * HW_IN;
            const float* wc = wb + c * 16;
            float y = 0.f, n = 0.f;
            for (int a = 0; a < nr; ++a)
                for (int d = 0; d < nc; ++d) {
                    const float wv = wc[ii[a] * 4 + jj[d]];
                    y += wv * xc[ri[a] * W_IN + cj[d]];
                    n += wv;
                }
            acc += y / n;
        }
    }

    acc += __shfl_xor(acc, 4);
    acc += __shfl_xor(acc, 2);
    acc += __shfl_xor(acc, 1);

    if (valid && cg == 0)
        out[((size_t)z * H_OUT + ho) * W_OUT + wo] = acc + bias[o];
}

extern "C" void kernel_launch(void* const* d_in, const int* in_sizes, int n_in,
                              void* d_out, int out_size, void* d_ws, size_t ws_size,
                              hipStream_t stream) {
    const float* x    = (const float*)d_in[0];
    const float* w    = (const float*)d_in[1];
    const float* bias = (const float*)d_in[2];
    float* out = (float*)d_out;

    dim3 bmain(16, 16, 1);
    dim3 gmain(36, O_OUT / O_TILE, 2);   // 36 x 12 x 2 = 864 blocks
    hipLaunchKernelGGL(nct_main, gmain, bmain, 0, stream, x, w, bias, out);

    dim3 bfix(256, 1, 1);
    dim3 gfix(24, 2 * O_OUT, 1);         // 24 x 96
    hipLaunchKernelGGL(nct_fix, gfix, bfix, 0, stream, x, w, bias, out);
}

// Round 4
// 44.350 us; speedup vs baseline: 1.9013x; 1.0561x over previous
//
#include <hip/hip_runtime.h>

#define C_IN  32
#define O_OUT 48
#define H_IN  96
#define W_IN  96
#define H_OUT 192
#define W_OUT 192
#define HW_IN (H_IN * W_IN)
#define O_TILE 4

// ---------------------------------------------------------------------------
// Prescale kernel: wsg[o][c][tap] = w[o][c][tap] / (interior norm of its class)
// Tap (i,j): i odd -> feeds even output rows; j odd -> feeds even output cols.
// ---------------------------------------------------------------------------
__global__ __launch_bounds__(256) void nct_prescale(
    const float* __restrict__ weight,  // [48,32,4,4]
    float* __restrict__ wsg)           // [48,32,16] prescaled
{
    const int oc = blockIdx.x * 256 + threadIdx.x;
    if (oc >= O_OUT * C_IN) return;
    const float* wc = weight + (size_t)oc * 16;
    float w[16];
    #pragma unroll
    for (int i = 0; i < 16; ++i) w[i] = wc[i];

    const float ree = 1.f / (w[5] + w[7] + w[13] + w[15]);  // even row, even col
    const float reo = 1.f / (w[4] + w[6] + w[12] + w[14]);  // even row, odd col
    const float roe = 1.f / (w[1] + w[3] + w[9]  + w[11]);  // odd row, even col
    const float roo = 1.f / (w[0] + w[2] + w[8]  + w[10]);  // odd row, odd col

    float* dst = wsg + (size_t)oc * 16;
    #pragma unroll
    for (int tap = 0; tap < 16; ++tap) {
        const int i = tap >> 2, j = tap & 3;
        const float r = (i & 1) ? ((j & 1) ? ree : reo)
                                : ((j & 1) ? roe : roo);
        dst[tap] = w[tap] * r;
    }
}

// ---------------------------------------------------------------------------
// Main kernel: all output pixels, interior norm folded into wsg, clamped x
// reads. Wrong only on the 1-pixel output frame; nct_fix repairs it.
// Weights are block-uniform -> s_load into SGPRs; FMAs are v_fmac(acc, s, v).
// ---------------------------------------------------------------------------
__global__ __launch_bounds__(256) void nct_main(
    const float* __restrict__ x,      // [B,32,96,96]
    const float* __restrict__ wsg,    // [48,32,16] prescaled
    const float* __restrict__ bias,   // [48]
    float* __restrict__ out)          // [B,48,192,192]
{
    const int b  = blockIdx.z;
    const int o0 = blockIdx.y * O_TILE;

    const int tx = threadIdx.x;   // 0..15
    const int ty = threadIdx.y;   // 0..15

    const int s = (blockIdx.x / 6) * 16 + ty;   // input row
    const int t = (blockIdx.x % 6) * 16 + tx;   // input col

    const int rm = (s > 0)        ? s - 1 : 0;
    const int rp = (s < H_IN - 1) ? s + 1 : H_IN - 1;
    const int cm = (t > 0)        ? t - 1 : 0;
    const int cp = (t < W_IN - 1) ? t + 1 : W_IN - 1;

    const float* xb = x + (size_t)b * (C_IN * HW_IN);
    const float* pm = xb + rm * W_IN;
    const float* p0 = xb + s  * W_IN;
    const float* pp = xb + rp * W_IN;

    const float* wbase = wsg + (size_t)o0 * (C_IN * 16);

    float acc[O_TILE][4];
    #pragma unroll
    for (int oi = 0; oi < O_TILE; ++oi)
        #pragma unroll
        for (int k = 0; k < 4; ++k) acc[oi][k] = 0.f;

    for (int c = 0; c < C_IN; ++c) {
        const float xmm = pm[cm], xm0 = pm[t], xmp = pm[cp];
        const float x0m = p0[cm], x00 = p0[t], x0p = p0[cp];
        const float xpm = pp[cm], xp0 = pp[t], xpp = pp[cp];

        #pragma unroll
        for (int oi = 0; oi < O_TILE; ++oi) {
            const float* w = wbase + ((size_t)oi * C_IN + c) * 16;  // uniform -> s_load
            acc[oi][0] += x00 * w[5] + x0m * w[7] + xm0 * w[13] + xmm * w[15];
            acc[oi][1] += x0p * w[4] + x00 * w[6] + xmp * w[12] + xm0 * w[14];
            acc[oi][2] += xp0 * w[1] + xpm * w[3] + x00 * w[9]  + x0m * w[11];
            acc[oi][3] += xpp * w[0] + xp0 * w[2] + x0p * w[8]  + x00 * w[10];
        }
        pm += HW_IN; p0 += HW_IN; pp += HW_IN;
    }

    #pragma unroll
    for (int oi = 0; oi < O_TILE; ++oi) {
        const float bv = bias[o0 + oi];
        float* op = out + ((size_t)((b * O_OUT + o0 + oi) * H_OUT) + 2 * s) * W_OUT + 2 * t;
        *(float2*)(op)         = make_float2(acc[oi][0] + bv, acc[oi][1] + bv);
        *(float2*)(op + W_OUT) = make_float2(acc[oi][2] + bv, acc[oi][3] + bv);
    }
}

// ---------------------------------------------------------------------------
// Frame fixup: exact recompute of the 764 frame pixels per (b,o) with true
// zero-padding and per-class norms. 8 lanes share one pixel (4 channels each),
// shfl_xor reduce.
// ---------------------------------------------------------------------------
__global__ __launch_bounds__(256) void nct_fix(
    const float* __restrict__ x,
    const float* __restrict__ weight,
    const float* __restrict__ bias,
    float* __restrict__ out)
{
    const int z = blockIdx.y;
    const int b = z / O_OUT;
    const int o = z % O_OUT;

    const int tid = threadIdx.x;
    const int pl  = tid >> 3;          // 0..31: pixel slot
    const int cg  = tid & 7;           // channel group
    const int p   = blockIdx.x * 32 + pl;

    float acc = 0.f;
    int ho = 0, wo = 0;
    const bool valid = (p < 764);
    if (valid) {
        if      (p < 192) { ho = 0;             wo = p;       }
        else if (p < 384) { ho = 191;           wo = p - 192; }
        else if (p < 574) { ho = 1 + (p - 384); wo = 0;       }
        else              { ho = 1 + (p - 574); wo = 191;     }

        const int s = ho >> 1, t = wo >> 1;

        int ii[2], ri[2], nr = 0;
        if (ho & 1) { ii[nr] = 2; ri[nr] = s; ++nr; if (s + 1 < H_IN) { ii[nr] = 0; ri[nr] = s + 1; ++nr; } }
        else        { ii[nr] = 1; ri[nr] = s; ++nr; if (s     >= 1  ) { ii[nr] = 3; ri[nr] = s - 1; ++nr; } }
        int jj[2], cj[2], nc = 0;
        if (wo & 1) { jj[nc] = 2; cj[nc] = t; ++nc; if (t + 1 < W_IN) { jj[nc] = 0; cj[nc] = t + 1; ++nc; } }
        else        { jj[nc] = 1; cj[nc] = t; ++nc; if (t     >= 1  ) { jj[nc] = 3; cj[nc] = t - 1; ++nc; } }

        const float* xb = x + (size_t)b * (C_IN * HW_IN);
        const float* wb = weight + (size_t)o * (C_IN * 16);

        #pragma unroll
        for (int cc = 0; cc < 4; ++cc) {
            const int c = cg * 4 + cc;
            const float* xc = xb + c * HW_IN;
            const float* wc = wb + c * 16;
            float y = 0.f, n = 0.f;
            for (int a = 0; a < nr; ++a)
                for (int d = 0; d < nc; ++d) {
                    const float wv = wc[ii[a] * 4 + jj[d]];
                    y += wv * xc[ri[a] * W_IN + cj[d]];
                    n += wv;
                }
            acc += y / n;
        }
    }

    acc += __shfl_xor(acc, 4);
    acc += __shfl_xor(acc, 2);
    acc += __shfl_xor(acc, 1);

    if (valid && cg == 0)
        out[((size_t)z * H_OUT + ho) * W_OUT + wo] = acc + bias[o];
}

extern "C" void kernel_launch(void* const* d_in, const int* in_sizes, int n_in,
                              void* d_out, int out_size, void* d_ws, size_t ws_size,
                              hipStream_t stream) {
    const float* x    = (const float*)d_in[0];
    const float* w    = (const float*)d_in[1];
    const float* bias = (const float*)d_in[2];
    float* out = (float*)d_out;
    float* wsg = (float*)d_ws;   // 48*32*16*4 = 96 KB

    dim3 bpre(256, 1, 1);
    dim3 gpre((O_OUT * C_IN + 255) / 256, 1, 1);   // 6 blocks
    hipLaunchKernelGGL(nct_prescale, gpre, bpre, 0, stream, w, wsg);

    dim3 bmain(16, 16, 1);
    dim3 gmain(36, O_OUT / O_TILE, 2);   // 36 x 12 x 2 = 864 blocks
    hipLaunchKernelGGL(nct_main, gmain, bmain, 0, stream, x, wsg, bias, out);

    dim3 bfix(256, 1, 1);
    dim3 gfix(24, 2 * O_OUT, 1);         // 24 x 96
    hipLaunchKernelGGL(nct_fix, gfix, bfix, 0, stream, x, w, bias, out);
}